// Round 3
// baseline (2672.568 us; speedup 1.0000x reference)
//
#include <hip/hip_runtime.h>
#include <math.h>

#define NTOK 131072
#define HDIM 256
#define DDIM 512
#define FDIM 1024
#define EDIM 16
#define TBLK 128
#define FCH  128
#define KCH  32
#define XST  132   // 132*4 = 528 B row stride: 16B-aligned, conflict-light

// min-waves/EU = 3 -> VGPR cap ~170: plenty for the ~110-float live set (no
// spill), while natural allocation ~128 still lets HW fit 4 waves/SIMD.
// (256,4) forced VGPR=64 -> 4.6 GB of scratch spill traffic (R2 post-mortem).
__global__ __launch_bounds__(256, 3)
void router_fused(const float* __restrict__ inp,
                  const float* __restrict__ cnd,
                  const float* __restrict__ W1,
                  const float* __restrict__ b1,
                  const float* __restrict__ W2,
                  const float* __restrict__ b2,
                  float* __restrict__ out)
{
    __shared__ float xs[KCH][XST];   // x tile, k-major: xs[k][t]
    __shared__ float w1s[KCH][FCH];  // W1 tile: w1s[k][f]

    const int tid = threadIdx.x;
    const int ty  = tid >> 4;   // 0..15: token group (8 tokens each)
    const int tx  = tid & 15;   // 0..15: f-cols {tx*4..+3, 64+tx*4..+3}; expert lane in epilogue
    const int t0  = blockIdx.x * TBLK;

    // running logits: lane tx owns expert tx for its 8 tokens
    float lg[8];
    {
        const float bb = b2[tx];
#pragma unroll
        for (int i = 0; i < 8; ++i) lg[i] = bb;
    }

    for (int fc = 0; fc < FDIM; fc += FCH) {
        float acc[8][8];
#pragma unroll
        for (int i = 0; i < 8; ++i)
#pragma unroll
            for (int j = 0; j < 8; ++j) acc[i][j] = 0.0f;

        for (int kc = 0; kc < DDIM; kc += KCH) {
            __syncthreads();
            // ---- stage x tile (transpose into xs[k][t]) ----
            {
                const float* src = (kc < HDIM)
                    ? (inp + (size_t)t0 * HDIM + kc)
                    : (cnd + (size_t)t0 * HDIM + (kc - HDIM));
                const int kl = (tid & 7) * 4;   // 0..28
                const int tl = tid >> 3;        // 0..31
#pragma unroll
                for (int p = 0; p < 4; ++p) {
                    const int trow = tl + p * 32;
                    const float4 v = *(const float4*)(src + (size_t)trow * HDIM + kl);
                    xs[kl + 0][trow] = v.x;
                    xs[kl + 1][trow] = v.y;
                    xs[kl + 2][trow] = v.z;
                    xs[kl + 3][trow] = v.w;
                }
            }
            // ---- stage W1 tile ----
            {
                const int fl = (tid & 31) * 4;  // 0..124
                const int kr = tid >> 5;        // 0..7
#pragma unroll
                for (int p = 0; p < 4; ++p)
                    *(float4*)&w1s[kr + p * 8][fl] =
                        *(const float4*)(W1 + (size_t)(kc + kr + p * 8) * FDIM + fc + fl);
            }
            __syncthreads();
            // ---- 128x128x32 register-blocked FMA ----
#pragma unroll 8
            for (int k = 0; k < KCH; ++k) {
                const float4 a0 = *(const float4*)&xs[k][ty * 8];
                const float4 a1 = *(const float4*)&xs[k][ty * 8 + 4];
                const float4 b0 = *(const float4*)&w1s[k][tx * 4];
                const float4 b4 = *(const float4*)&w1s[k][64 + tx * 4];
                const float av[8] = {a0.x, a0.y, a0.z, a0.w, a1.x, a1.y, a1.z, a1.w};
                const float bv[8] = {b0.x, b0.y, b0.z, b0.w, b4.x, b4.y, b4.z, b4.w};
#pragma unroll
                for (int i = 0; i < 8; ++i)
#pragma unroll
                    for (int j = 0; j < 8; ++j)
                        acc[i][j] = fmaf(av[i], bv[j], acc[i][j]);
            }
        }

        // ---- bias + exact GELU ----
        {
            const float4 ba = *(const float4*)(b1 + fc + tx * 4);
            const float4 bc = *(const float4*)(b1 + fc + 64 + tx * 4);
            const float bias[8] = {ba.x, ba.y, ba.z, ba.w, bc.x, bc.y, bc.z, bc.w};
#pragma unroll
            for (int i = 0; i < 8; ++i)
#pragma unroll
                for (int j = 0; j < 8; ++j) {
                    const float v = acc[i][j] + bias[j];
                    acc[i][j] = 0.5f * v * (1.0f + erff(v * 0.70710678118654752f));
                }
        }

        // ---- GEMM2 partial logits + deterministic 16-lane butterfly reduce ----
#pragma unroll
        for (int q = 0; q < 4; ++q) {
            float w2q[8][4];
#pragma unroll
            for (int j = 0; j < 8; ++j) {
                const int f = fc + ((j < 4) ? (tx * 4 + j) : (64 + tx * 4 + (j - 4)));
                const float4 w = *(const float4*)(W2 + (size_t)f * EDIM + q * 4);
                w2q[j][0] = w.x; w2q[j][1] = w.y; w2q[j][2] = w.z; w2q[j][3] = w.w;
            }
#pragma unroll
            for (int i = 0; i < 8; ++i) {
                float pe[4] = {0.0f, 0.0f, 0.0f, 0.0f};
#pragma unroll
                for (int j = 0; j < 8; ++j)
#pragma unroll
                    for (int e = 0; e < 4; ++e)
                        pe[e] = fmaf(acc[i][j], w2q[j][e], pe[e]);
#pragma unroll
                for (int m = 1; m < 16; m <<= 1)
#pragma unroll
                    for (int e = 0; e < 4; ++e)
                        pe[e] += __shfl_xor(pe[e], m, 64);
                if ((tx >> 2) == q) lg[i] += pe[tx & 3];
            }
        }
    }

    // ---- softmax + clip + top-2 + writes: lane tx = expert tx, tokens ty*8+i ----
#pragma unroll
    for (int i = 0; i < 8; ++i) {
        const int t = t0 + ty * 8 + i;
        // max over experts (16-lane butterfly)
        float mx = lg[i];
#pragma unroll
        for (int m = 1; m < 16; m <<= 1) mx = fmaxf(mx, __shfl_xor(mx, m, 64));
        float p = expf(lg[i] - mx);
        float s = p;
#pragma unroll
        for (int m = 1; m < 16; m <<= 1) s += __shfl_xor(s, m, 64);
        float pr = p / s;
        pr = fminf(fmaxf(pr, 1e-9f), 1.0f - 1e-9f);

        // top-1: max value, lowest index on ties
        float v1 = pr; int i1 = tx;
#pragma unroll
        for (int m = 1; m < 16; m <<= 1) {
            const float vo = __shfl_xor(v1, m, 64);
            const int   io = __shfl_xor(i1, m, 64);
            if (vo > v1 || (vo == v1 && io < i1)) { v1 = vo; i1 = io; }
        }
        // top-2: exclude i1
        float v2 = (tx == i1) ? -1.0f : pr; int i2 = tx;
#pragma unroll
        for (int m = 1; m < 16; m <<= 1) {
            const float vo = __shfl_xor(v2, m, 64);
            const int   io = __shfl_xor(i2, m, 64);
            if (vo > v2 || (vo == v2 && io < i2)) { v2 = vo; i2 = io; }
        }
        const float rs = 1.0f / (v1 + v2);

        float* om  = out + (size_t)t * EDIM;
        float* orp = out + (size_t)NTOK * 18 + (size_t)t * EDIM;
        float* opf = out + (size_t)NTOK * 34 + (size_t)t * EDIM;
        om[tx]  = (tx == i1 || tx == i2) ? 1.0f : 0.0f;
        orp[tx] = (tx == i1) ? v1 * rs : ((tx == i2) ? v2 * rs : 0.0f);
        opf[tx] = pr;
        if (tx == 0) {
            float2* oi = (float2*)(out + (size_t)NTOK * 16 + (size_t)t * 2);
            *oi = make_float2((float)i1, (float)i2);
        }
    }
}

extern "C" void kernel_launch(void* const* d_in, const int* in_sizes, int n_in,
                              void* d_out, int out_size, void* d_ws, size_t ws_size,
                              hipStream_t stream)
{
    const float* inp = (const float*)d_in[0];
    const float* cnd = (const float*)d_in[1];
    const float* W1  = (const float*)d_in[2];
    const float* b1  = (const float*)d_in[3];
    const float* W2  = (const float*)d_in[4];
    const float* b2  = (const float*)d_in[5];
    float* out = (float*)d_out;

    dim3 grid(NTOK / TBLK), block(256);
    hipLaunchKernelGGL(router_fused, grid, block, 0, stream,
                       inp, cnd, W1, b1, W2, b2, out);
}

// Round 4
// 1913.069 us; speedup vs baseline: 1.3970x; 1.3970x over previous
//
#include <hip/hip_runtime.h>
#include <math.h>

#define NTOK 131072
#define HDIM 256
#define DDIM 512
#define FDIM 1024
#define EDIM 16
#define TBLK 128
#define FCH  128
#define KCH  32
#define XST  132   // 132*4 = 528 B row stride: 16B-aligned, conflict-light

// (256,2): the ONLY empirically no-spill bound (R1: VGPR=128, WRITE=25MB).
// (256,4) -> VGPR=64, (256,3) -> VGPR=84: both spill ~2.3GB scratch traffic.
__global__ __launch_bounds__(256, 2)
void router_fused(const float* __restrict__ inp,
                  const float* __restrict__ cnd,
                  const float* __restrict__ W1,
                  const float* __restrict__ b1,
                  const float* __restrict__ W2,
                  const float* __restrict__ b2,
                  float* __restrict__ out)
{
    __shared__ float xs[KCH][XST];   // x tile, k-major: xs[k][t]
    __shared__ float w1s[KCH][FCH];  // W1 tile: w1s[k][f]

    const int tid = threadIdx.x;
    const int ty  = tid >> 4;   // 0..15: token group (8 tokens each)
    const int tx  = tid & 15;   // 0..15: f-cols {tx*4..+3, 64+tx*4..+3}; expert lane in epilogue
    const int t0  = blockIdx.x * TBLK;

    // running logits: lane tx owns expert tx for its 8 tokens
    float lg[8];
    {
        const float bb = b2[tx];
#pragma unroll
        for (int i = 0; i < 8; ++i) lg[i] = bb;
    }

    for (int fc = 0; fc < FDIM; fc += FCH) {
        float acc[8][8];
#pragma unroll
        for (int i = 0; i < 8; ++i)
#pragma unroll
            for (int j = 0; j < 8; ++j) acc[i][j] = 0.0f;

        for (int kc = 0; kc < DDIM; kc += KCH) {
            __syncthreads();
            // ---- stage x tile (transpose into xs[k][t]) ----
            {
                const float* src = (kc < HDIM)
                    ? (inp + (size_t)t0 * HDIM + kc)
                    : (cnd + (size_t)t0 * HDIM + (kc - HDIM));
                const int kl = (tid & 7) * 4;   // 0..28
                const int tl = tid >> 3;        // 0..31
#pragma unroll
                for (int p = 0; p < 4; ++p) {
                    const int trow = tl + p * 32;
                    const float4 v = *(const float4*)(src + (size_t)trow * HDIM + kl);
                    xs[kl + 0][trow] = v.x;
                    xs[kl + 1][trow] = v.y;
                    xs[kl + 2][trow] = v.z;
                    xs[kl + 3][trow] = v.w;
                }
            }
            // ---- stage W1 tile ----
            {
                const int fl = (tid & 31) * 4;  // 0..124
                const int kr = tid >> 5;        // 0..7
#pragma unroll
                for (int p = 0; p < 4; ++p)
                    *(float4*)&w1s[kr + p * 8][fl] =
                        *(const float4*)(W1 + (size_t)(kc + kr + p * 8) * FDIM + fc + fl);
            }
            __syncthreads();
            // ---- 128x128x32 register-blocked FMA ----
#pragma unroll 8
            for (int k = 0; k < KCH; ++k) {
                const float4 a0 = *(const float4*)&xs[k][ty * 8];
                const float4 a1 = *(const float4*)&xs[k][ty * 8 + 4];
                const float4 b0 = *(const float4*)&w1s[k][tx * 4];
                const float4 b4 = *(const float4*)&w1s[k][64 + tx * 4];
                const float av[8] = {a0.x, a0.y, a0.z, a0.w, a1.x, a1.y, a1.z, a1.w};
                const float bv[8] = {b0.x, b0.y, b0.z, b0.w, b4.x, b4.y, b4.z, b4.w};
#pragma unroll
                for (int i = 0; i < 8; ++i)
#pragma unroll
                    for (int j = 0; j < 8; ++j)
                        acc[i][j] = fmaf(av[i], bv[j], acc[i][j]);
            }
        }

        // ---- bias + exact GELU ----
        {
            const float4 ba = *(const float4*)(b1 + fc + tx * 4);
            const float4 bc = *(const float4*)(b1 + fc + 64 + tx * 4);
            const float bias[8] = {ba.x, ba.y, ba.z, ba.w, bc.x, bc.y, bc.z, bc.w};
#pragma unroll
            for (int i = 0; i < 8; ++i)
#pragma unroll
                for (int j = 0; j < 8; ++j) {
                    const float v = acc[i][j] + bias[j];
                    acc[i][j] = 0.5f * v * (1.0f + erff(v * 0.70710678118654752f));
                }
        }

        // ---- GEMM2 partial logits + deterministic 16-lane butterfly reduce ----
#pragma unroll
        for (int q = 0; q < 4; ++q) {
            float w2q[8][4];
#pragma unroll
            for (int j = 0; j < 8; ++j) {
                const int f = fc + ((j < 4) ? (tx * 4 + j) : (64 + tx * 4 + (j - 4)));
                const float4 w = *(const float4*)(W2 + (size_t)f * EDIM + q * 4);
                w2q[j][0] = w.x; w2q[j][1] = w.y; w2q[j][2] = w.z; w2q[j][3] = w.w;
            }
#pragma unroll
            for (int i = 0; i < 8; ++i) {
                float pe[4] = {0.0f, 0.0f, 0.0f, 0.0f};
#pragma unroll
                for (int j = 0; j < 8; ++j)
#pragma unroll
                    for (int e = 0; e < 4; ++e)
                        pe[e] = fmaf(acc[i][j], w2q[j][e], pe[e]);
#pragma unroll
                for (int m = 1; m < 16; m <<= 1)
#pragma unroll
                    for (int e = 0; e < 4; ++e)
                        pe[e] += __shfl_xor(pe[e], m, 64);
                if ((tx >> 2) == q) lg[i] += pe[tx & 3];
            }
        }
    }

    // ---- softmax + clip + top-2 + writes: lane tx = expert tx, tokens ty*8+i ----
#pragma unroll
    for (int i = 0; i < 8; ++i) {
        const int t = t0 + ty * 8 + i;
        // max over experts (16-lane butterfly)
        float mx = lg[i];
#pragma unroll
        for (int m = 1; m < 16; m <<= 1) mx = fmaxf(mx, __shfl_xor(mx, m, 64));
        float p = expf(lg[i] - mx);
        float s = p;
#pragma unroll
        for (int m = 1; m < 16; m <<= 1) s += __shfl_xor(s, m, 64);
        float pr = p / s;
        pr = fminf(fmaxf(pr, 1e-9f), 1.0f - 1e-9f);

        // top-1: max value, lowest index on ties
        float v1 = pr; int i1 = tx;
#pragma unroll
        for (int m = 1; m < 16; m <<= 1) {
            const float vo = __shfl_xor(v1, m, 64);
            const int   io = __shfl_xor(i1, m, 64);
            if (vo > v1 || (vo == v1 && io < i1)) { v1 = vo; i1 = io; }
        }
        // top-2: exclude i1
        float v2 = (tx == i1) ? -1.0f : pr; int i2 = tx;
#pragma unroll
        for (int m = 1; m < 16; m <<= 1) {
            const float vo = __shfl_xor(v2, m, 64);
            const int   io = __shfl_xor(i2, m, 64);
            if (vo > v2 || (vo == v2 && io < i2)) { v2 = vo; i2 = io; }
        }
        const float rs = 1.0f / (v1 + v2);

        float* om  = out + (size_t)t * EDIM;
        float* orp = out + (size_t)NTOK * 18 + (size_t)t * EDIM;
        float* opf = out + (size_t)NTOK * 34 + (size_t)t * EDIM;
        om[tx]  = (tx == i1 || tx == i2) ? 1.0f : 0.0f;
        orp[tx] = (tx == i1) ? v1 * rs : ((tx == i2) ? v2 * rs : 0.0f);
        opf[tx] = pr;
        if (tx == 0) {
            float2* oi = (float2*)(out + (size_t)NTOK * 16 + (size_t)t * 2);
            *oi = make_float2((float)i1, (float)i2);
        }
    }
}

extern "C" void kernel_launch(void* const* d_in, const int* in_sizes, int n_in,
                              void* d_out, int out_size, void* d_ws, size_t ws_size,
                              hipStream_t stream)
{
    const float* inp = (const float*)d_in[0];
    const float* cnd = (const float*)d_in[1];
    const float* W1  = (const float*)d_in[2];
    const float* b1  = (const float*)d_in[3];
    const float* W2  = (const float*)d_in[4];
    const float* b2  = (const float*)d_in[5];
    float* out = (float*)d_out;

    dim3 grid(NTOK / TBLK), block(256);
    hipLaunchKernelGGL(router_fused, grid, block, 0, stream,
                       inp, cnd, W1, b1, W2, b2, out);
}

// Round 9
// 1092.285 us; speedup vs baseline: 2.4468x; 1.7514x over previous
//
#include <hip/hip_runtime.h>
#include <math.h>

#define NTOK 131072
#define HDIM 256
#define DDIM 512
#define FDIM 1024
#define EDIM 16
#define TBLK 128
#define HST  67    // hs f32 row stride: 67*4B -> 8-token stride hits distinct banks

typedef __attribute__((ext_vector_type(8))) _Float16 v8h;
typedef __attribute__((ext_vector_type(4))) _Float16 v4h;
typedef __attribute__((ext_vector_type(4))) float v4f;

// f32 -> fp16 hi + scaled-lo split: v ~= h + l/2048, error <= 2^-22 |v|
__device__ __forceinline__ void f2h2(float v, _Float16& h, _Float16& l) {
    h = (_Float16)v;
    l = (_Float16)((v - (float)h) * 2048.0f);
}

// LDS (55296 B): xs_h[128][72]f16 @0 (18432), xs_l @18432,
//                ws_h[64][72]f16 @36864 (9216), ws_l @46080
// GEMM2 phase:   hs f32 [128][67] aliases @0 (34304 <= 36864)
__global__ __launch_bounds__(256, 2)
void router_mfma(const float* __restrict__ inp,
                 const float* __restrict__ cnd,
                 const float* __restrict__ W1,
                 const float* __restrict__ b1,
                 const float* __restrict__ W2,
                 const float* __restrict__ b2,
                 float* __restrict__ out)
{
    __shared__ __align__(16) char smem[55296];
    _Float16* xs_h = (_Float16*)(smem);
    _Float16* xs_l = (_Float16*)(smem + 18432);
    _Float16* ws_h = (_Float16*)(smem + 36864);
    _Float16* ws_l = (_Float16*)(smem + 46080);
    float*    hs   = (float*)(smem);            // alias xs (barrier-separated)

    const int tid  = threadIdx.x;
    const int lane = tid & 63;
    const int w    = tid >> 6;     // wave 0..3
    const int wr   = w >> 1;       // token half (64)
    const int wc   = w & 1;        // F half (32 within 64-chunk)
    const int l15  = lane & 15;
    const int l4   = lane >> 4;
    const int t0   = blockIdx.x * TBLK;
    const int ty   = tid >> 4;     // GEMM2/epilogue: token group (8 tokens)
    const int tx   = tid & 15;     // GEMM2/epilogue: expert lane / f-col group

    float lg[8];
    {
        const float bb = b2[tx];
#pragma unroll
        for (int i = 0; i < 8; ++i) lg[i] = bb;
    }

    for (int fc = 0; fc < FDIM; fc += 64) {
        v4f acc_hh[4][2], acc_lo[4][2];
#pragma unroll
        for (int mf = 0; mf < 4; ++mf)
#pragma unroll
            for (int nf = 0; nf < 2; ++nf) {
                acc_hh[mf][nf] = (v4f){0.f,0.f,0.f,0.f};
                acc_lo[mf][nf] = (v4f){0.f,0.f,0.f,0.f};
            }

        for (int kc = 0; kc < DDIM; kc += 64) {
            __syncthreads();   // prior-phase LDS reads (MFMA / GEMM2-hs) done
            // ---- stage x tile [128 tok][64 k] as fp16 hi / scaled-lo ----
            {
                const float* src = (kc < HDIM)
                    ? (inp + (size_t)t0 * HDIM + kc)
                    : (cnd + (size_t)t0 * HDIM + (kc - HDIM));
                const int kq = tid & 15, tb = tid >> 4;
#pragma unroll
                for (int s = 0; s < 8; ++s) {
                    const int tok = tb + 16 * s;
                    const float4 v = *(const float4*)(src + (size_t)tok * HDIM + kq * 4);
                    _Float16 h0, l0, h1, l1, h2, l2, h3, l3;
                    f2h2(v.x, h0, l0); f2h2(v.y, h1, l1);
                    f2h2(v.z, h2, l2); f2h2(v.w, h3, l3);
                    v4h hh, hl;
                    hh[0] = h0; hh[1] = h1; hh[2] = h2; hh[3] = h3;
                    hl[0] = l0; hl[1] = l1; hl[2] = l2; hl[3] = l3;
                    *(v4h*)(xs_h + tok * 72 + kq * 4) = hh;
                    *(v4h*)(xs_l + tok * 72 + kq * 4) = hl;
                }
            }
            // ---- stage W1 tile [64 k][64 F] transposed -> ws[F][k] ----
            {
                const int fcl = tid & 63, g = tid >> 6;    // g 0..3
#pragma unroll
                for (int s = 0; s < 4; ++s) {
                    const int kb = 4 * (4 * s + g);        // {0,4,...,60}
                    const float u0 = W1[(size_t)(kc + kb + 0) * FDIM + fc + fcl];
                    const float u1 = W1[(size_t)(kc + kb + 1) * FDIM + fc + fcl];
                    const float u2 = W1[(size_t)(kc + kb + 2) * FDIM + fc + fcl];
                    const float u3 = W1[(size_t)(kc + kb + 3) * FDIM + fc + fcl];
                    _Float16 h0, l0, h1, l1, h2, l2, h3, l3;
                    f2h2(u0, h0, l0); f2h2(u1, h1, l1);
                    f2h2(u2, h2, l2); f2h2(u3, h3, l3);
                    v4h hh, hl;
                    hh[0] = h0; hh[1] = h1; hh[2] = h2; hh[3] = h3;
                    hl[0] = l0; hl[1] = l1; hl[2] = l2; hl[3] = l3;
                    *(v4h*)(ws_h + fcl * 72 + kb) = hh;
                    *(v4h*)(ws_l + fcl * 72 + kb) = hl;
                }
            }
            __syncthreads();
            // ---- MFMA 16x16x32 f16: hh->acc_hh ; (lo*wh + hh*lo)->acc_lo ----
#pragma unroll
            for (int kk = 0; kk < 2; ++kk) {
                v8h ah[4], al[4];
#pragma unroll
                for (int mf = 0; mf < 4; ++mf) {
                    const int off = (64 * wr + 16 * mf + l15) * 72 + 32 * kk + 8 * l4;
                    ah[mf] = *(const v8h*)(xs_h + off);
                    al[mf] = *(const v8h*)(xs_l + off);
                }
                v8h bh[2], bl[2];
#pragma unroll
                for (int nf = 0; nf < 2; ++nf) {
                    const int off = (32 * wc + 16 * nf + l15) * 72 + 32 * kk + 8 * l4;
                    bh[nf] = *(const v8h*)(ws_h + off);
                    bl[nf] = *(const v8h*)(ws_l + off);
                }
#pragma unroll
                for (int mf = 0; mf < 4; ++mf)
#pragma unroll
                    for (int nf = 0; nf < 2; ++nf) {
                        acc_hh[mf][nf] = __builtin_amdgcn_mfma_f32_16x16x32_f16(ah[mf], bh[nf], acc_hh[mf][nf], 0, 0, 0);
                        acc_lo[mf][nf] = __builtin_amdgcn_mfma_f32_16x16x32_f16(al[mf], bh[nf], acc_lo[mf][nf], 0, 0, 0);
                        acc_lo[mf][nf] = __builtin_amdgcn_mfma_f32_16x16x32_f16(ah[mf], bl[nf], acc_lo[mf][nf], 0, 0, 0);
                    }
            }
        }
        __syncthreads();   // all xs/ws MFMA reads done; hs may alias xs now

        // ---- combine + bias + exact GELU -> hs (f32, stride 67) ----
        {
            float b1v[2];
#pragma unroll
            for (int nf = 0; nf < 2; ++nf)
                b1v[nf] = b1[fc + 32 * wc + 16 * nf + l15];
#pragma unroll
            for (int mf = 0; mf < 4; ++mf)
#pragma unroll
                for (int nf = 0; nf < 2; ++nf)
#pragma unroll
                    for (int r = 0; r < 4; ++r) {
                        const float v = acc_hh[mf][nf][r]
                                      + 4.8828125e-4f * acc_lo[mf][nf][r]
                                      + b1v[nf];
                        const float g = 0.5f * v * (1.0f + erff(v * 0.70710678118654752f));
                        const int tok  = 64 * wr + 16 * mf + 4 * l4 + r;
                        const int fcol = 32 * wc + 16 * nf + l15;
                        hs[tok * HST + fcol] = g;
                    }
        }
        __syncthreads();

        // ---- GEMM2 (f32 VALU, R4-proven): thread (ty,tx), f-cols tx*4..+3 ----
        float h_ij[8][4];
#pragma unroll
        for (int i = 0; i < 8; ++i)
#pragma unroll
            for (int j = 0; j < 4; ++j)
                h_ij[i][j] = hs[(ty * 8 + i) * HST + tx * 4 + j];

#pragma unroll
        for (int q = 0; q < 4; ++q) {
            float w2q[4][4];
#pragma unroll
            for (int j = 0; j < 4; ++j) {
                const float4 wv = *(const float4*)(W2 + (size_t)(fc + tx * 4 + j) * EDIM + q * 4);
                w2q[j][0] = wv.x; w2q[j][1] = wv.y; w2q[j][2] = wv.z; w2q[j][3] = wv.w;
            }
#pragma unroll
            for (int i = 0; i < 8; ++i) {
                float pe[4] = {0.0f, 0.0f, 0.0f, 0.0f};
#pragma unroll
                for (int j = 0; j < 4; ++j)
#pragma unroll
                    for (int e = 0; e < 4; ++e)
                        pe[e] = fmaf(h_ij[i][j], w2q[j][e], pe[e]);
#pragma unroll
                for (int m = 1; m < 16; m <<= 1)
#pragma unroll
                    for (int e = 0; e < 4; ++e)
                        pe[e] += __shfl_xor(pe[e], m, 64);
                if ((tx >> 2) == q) lg[i] += pe[tx & 3];
            }
        }
    }

    // ---- softmax + clip + top-2 + writes (R4 verbatim) ----
#pragma unroll
    for (int i = 0; i < 8; ++i) {
        const int t = t0 + ty * 8 + i;
        float mx = lg[i];
#pragma unroll
        for (int m = 1; m < 16; m <<= 1) mx = fmaxf(mx, __shfl_xor(mx, m, 64));
        float p = expf(lg[i] - mx);
        float s = p;
#pragma unroll
        for (int m = 1; m < 16; m <<= 1) s += __shfl_xor(s, m, 64);
        float pr = p / s;
        pr = fminf(fmaxf(pr, 1e-9f), 1.0f - 1e-9f);

        float v1 = pr; int i1 = tx;
#pragma unroll
        for (int m = 1; m < 16; m <<= 1) {
            const float vo = __shfl_xor(v1, m, 64);
            const int   io = __shfl_xor(i1, m, 64);
            if (vo > v1 || (vo == v1 && io < i1)) { v1 = vo; i1 = io; }
        }
        float v2 = (tx == i1) ? -1.0f : pr; int i2 = tx;
#pragma unroll
        for (int m = 1; m < 16; m <<= 1) {
            const float vo = __shfl_xor(v2, m, 64);
            const int   io = __shfl_xor(i2, m, 64);
            if (vo > v2 || (vo == v2 && io < i2)) { v2 = vo; i2 = io; }
        }
        const float rs = 1.0f / (v1 + v2);

        float* om  = out + (size_t)t * EDIM;
        float* orp = out + (size_t)NTOK * 18 + (size_t)t * EDIM;
        float* opf = out + (size_t)NTOK * 34 + (size_t)t * EDIM;
        om[tx]  = (tx == i1 || tx == i2) ? 1.0f : 0.0f;
        orp[tx] = (tx == i1) ? v1 * rs : ((tx == i2) ? v2 * rs : 0.0f);
        opf[tx] = pr;
        if (tx == 0) {
            float2* oi = (float2*)(out + (size_t)NTOK * 16 + (size_t)t * 2);
            *oi = make_float2((float)i1, (float)i2);
        }
    }
}

extern "C" void kernel_launch(void* const* d_in, const int* in_sizes, int n_in,
                              void* d_out, int out_size, void* d_ws, size_t ws_size,
                              hipStream_t stream)
{
    const float* inp = (const float*)d_in[0];
    const float* cnd = (const float*)d_in[1];
    const float* W1  = (const float*)d_in[2];
    const float* b1  = (const float*)d_in[3];
    const float* W2  = (const float*)d_in[4];
    const float* b2  = (const float*)d_in[5];
    float* out = (float*)d_out;

    dim3 grid(NTOK / TBLK), block(256);
    hipLaunchKernelGGL(router_mfma, grid, block, 0, stream,
                       inp, cnd, W1, b1, W2, b2, out);
}